// Round 1
// baseline (1507.554 us; speedup 1.0000x reference)
//
#include <hip/hip_runtime.h>
#include <math.h>

// ---------------------------------------------------------------------------
// TacticalGAT: 2-layer GATv2 (H1=4,C1=32 concat; H=1,C2=64 mean) + mean-pool
// + 2-layer MLP head.  f32 throughout.  Segment-softmax computed WITHOUT the
// segment-max pass (shift-invariant; scores are O(1) so exp() cannot overflow).
// ---------------------------------------------------------------------------

// ---------------- self-loop attr (fill_value='mean') -----------------------
__global__ void loop_accum_k(const int* __restrict__ dst, const float* __restrict__ eattr,
                             float* __restrict__ loopsum, float* __restrict__ cnt, int E) {
  int e = blockIdx.x * blockDim.x + threadIdx.x;
  if (e >= E) return;
  int d = dst[e];
  atomicAdd(&cnt[d], 1.0f);
  atomicAdd(&loopsum[d * 3 + 0], eattr[e * 3 + 0]);
  atomicAdd(&loopsum[d * 3 + 1], eattr[e * 3 + 1]);
  atomicAdd(&loopsum[d * 3 + 2], eattr[e * 3 + 2]);
}

__global__ void loop_norm_k(float* __restrict__ loopsum, const float* __restrict__ cnt, int N) {
  int i = blockIdx.x * blockDim.x + threadIdx.x;
  if (i >= N) return;
  float inv = 1.0f / fmaxf(cnt[i], 1.0f);
  loopsum[i * 3 + 0] *= inv;
  loopsum[i * 3 + 1] *= inv;
  loopsum[i * 3 + 2] *= inv;
}

// ---------------- node linear: out[n,j] = sum_k X[n,k]*W[j,k] + b[j] --------
// K = 128 fixed. 4 rows x 4 cols register tile per thread; W staged in LDS in
// two K-halves (keeps static LDS under 64 KB).
template <int J, int RB>
__global__ __launch_bounds__(256) void node_linear_k(
    const float* __restrict__ X, const float* __restrict__ W,
    const float* __restrict__ bias, float* __restrict__ out, int nrows) {
  constexpr int K = 128, KB = 64;
  constexpr int JG = J / 4;   // col groups of 4
  constexpr int RG = RB / 4;  // row groups of 4 (JG*RG == 256)
  __shared__ __align__(16) float sW[KB][J];
  __shared__ float sX[RB][K + 1];

  int n0 = blockIdx.x * RB;
  for (int idx = threadIdx.x; idx < RB * K; idx += 256) {
    int r = idx >> 7, k = idx & 127;
    int n = n0 + r;
    sX[r][k] = (n < nrows) ? X[(size_t)n * K + k] : 0.0f;
  }
  int jg = threadIdx.x % JG;
  int rg = threadIdx.x / JG;

  float acc[4][4] = {};
  for (int kb = 0; kb < 2; ++kb) {
    __syncthreads();
    for (int idx = threadIdx.x; idx < KB * J; idx += 256) {
      int j = idx % J, k = idx / J;
      sW[k][j] = W[j * K + kb * KB + k];
    }
    __syncthreads();
#pragma unroll
    for (int k = 0; k < KB; ++k) {
      float4 w4 = *(const float4*)&sW[k][jg * 4];
#pragma unroll
      for (int i = 0; i < 4; ++i) {
        float xv = sX[rg * 4 + i][kb * KB + k];
        acc[i][0] += xv * w4.x;
        acc[i][1] += xv * w4.y;
        acc[i][2] += xv * w4.z;
        acc[i][3] += xv * w4.w;
      }
    }
  }
  float4 bv = *(const float4*)&bias[jg * 4];
#pragma unroll
  for (int i = 0; i < 4; ++i) {
    int n = n0 + rg * 4 + i;
    if (n < nrows) {
      float4 o;
      o.x = acc[i][0] + bv.x;
      o.y = acc[i][1] + bv.y;
      o.z = acc[i][2] + bv.z;
      o.w = acc[i][3] + bv.w;
      *(float4*)&out[(size_t)n * J + jg * 4] = o;
    }
  }
}

// ---------------- layer-1 edge scores (H=4, C=32) ---------------------------
// half-wave (32 lanes) per edge: lane = channel, 4 heads looped; butterfly
// reduce within 32 lanes; lanes 0..3 write ex and atomicAdd denom.
__global__ void score1_k(const int* __restrict__ src, const int* __restrict__ dst,
                         const float* __restrict__ eattr, const float* __restrict__ loop_attr,
                         const float* __restrict__ xl, const float* __restrict__ xr,
                         const float* __restrict__ We, const float* __restrict__ att,
                         float* __restrict__ exbuf, float* __restrict__ denom,
                         int E, int Etot) {
  int wid = (blockIdx.x * 256 + threadIdx.x) >> 6;
  int lane = threadIdx.x & 63;
  int sub = lane & 31, half = lane >> 5;
  int e = wid * 2 + half;
  bool active = e < Etot;
  int s_ = 0, d_ = 0;
  float ea0 = 0, ea1 = 0, ea2 = 0;
  if (active) {
    if (e < E) {
      s_ = src[e]; d_ = dst[e];
      ea0 = eattr[e * 3 + 0]; ea1 = eattr[e * 3 + 1]; ea2 = eattr[e * 3 + 2];
    } else {
      s_ = d_ = e - E;
      const float* la = &loop_attr[(size_t)(e - E) * 3];
      ea0 = la[0]; ea1 = la[1]; ea2 = la[2];
    }
  }
  float s_own = 0.0f;
#pragma unroll
  for (int h = 0; h < 4; ++h) {
    float m = 0.0f;
    if (active) {
      int c = h * 32 + sub;
      float ee = ea0 * We[c * 3 + 0] + ea1 * We[c * 3 + 1] + ea2 * We[c * 3 + 2];
      float v = xl[(size_t)s_ * 128 + c] + xr[(size_t)d_ * 128 + c] + ee;
      v = v > 0.0f ? v : 0.2f * v;
      m = v * att[c];
    }
    for (int off = 16; off; off >>= 1) m += __shfl_xor(m, off);
    if (sub == h) s_own = m;
  }
  if (active && sub < 4) {
    float ex = expf(s_own);
    exbuf[(size_t)e * 4 + sub] = ex;
    atomicAdd(&denom[(size_t)d_ * 4 + sub], ex);
  }
}

// ---------------- layer-2 edge scores (H=1, C=64) ---------------------------
__global__ void score2_k(const int* __restrict__ src, const int* __restrict__ dst,
                         const float* __restrict__ eattr, const float* __restrict__ loop_attr,
                         const float* __restrict__ xl, const float* __restrict__ xr,
                         const float* __restrict__ We, const float* __restrict__ att,
                         float* __restrict__ exbuf, float* __restrict__ denom,
                         int E, int Etot) {
  int wid = (blockIdx.x * 256 + threadIdx.x) >> 6;
  int lane = threadIdx.x & 63;
  int e = wid;
  if (e >= Etot) return;
  int s_, d_;
  float ea0, ea1, ea2;
  if (e < E) {
    s_ = src[e]; d_ = dst[e];
    ea0 = eattr[e * 3 + 0]; ea1 = eattr[e * 3 + 1]; ea2 = eattr[e * 3 + 2];
  } else {
    s_ = d_ = e - E;
    const float* la = &loop_attr[(size_t)(e - E) * 3];
    ea0 = la[0]; ea1 = la[1]; ea2 = la[2];
  }
  int c = lane;
  float ee = ea0 * We[c * 3 + 0] + ea1 * We[c * 3 + 1] + ea2 * We[c * 3 + 2];
  float v = xl[(size_t)s_ * 64 + c] + xr[(size_t)d_ * 64 + c] + ee;
  v = v > 0.0f ? v : 0.2f * v;
  float m = v * att[c];
  for (int off = 32; off; off >>= 1) m += __shfl_xor(m, off);
  if (lane == 0) {
    float ex = expf(m);
    exbuf[e] = ex;
    atomicAdd(&denom[d_], ex);
  }
}

// ---------------- aggregation -----------------------------------------------
__global__ void agg1_k(const int* __restrict__ src, const int* __restrict__ dst,
                       const float* __restrict__ xl, const float* __restrict__ exbuf,
                       const float* __restrict__ denom, float* __restrict__ out,
                       int E, int Etot) {
  int wid = (blockIdx.x * 256 + threadIdx.x) >> 6;
  int lane = threadIdx.x & 63;
  int e = wid;
  if (e >= Etot) return;
  int s_ = (e < E) ? src[e] : e - E;
  int d_ = (e < E) ? dst[e] : e - E;
#pragma unroll
  for (int q = 0; q < 2; ++q) {
    int j = q * 64 + lane;
    int h = j >> 5;
    float alpha = exbuf[(size_t)e * 4 + h] / denom[(size_t)d_ * 4 + h];
    atomicAdd(&out[(size_t)d_ * 128 + j], alpha * xl[(size_t)s_ * 128 + j]);
  }
}

__global__ void agg2_k(const int* __restrict__ src, const int* __restrict__ dst,
                       const float* __restrict__ xl, const float* __restrict__ exbuf,
                       const float* __restrict__ denom, float* __restrict__ out,
                       int E, int Etot) {
  int wid = (blockIdx.x * 256 + threadIdx.x) >> 6;
  int lane = threadIdx.x & 63;
  int e = wid;
  if (e >= Etot) return;
  int s_ = (e < E) ? src[e] : e - E;
  int d_ = (e < E) ? dst[e] : e - E;
  float alpha = exbuf[e] / denom[d_];
  atomicAdd(&out[(size_t)d_ * 64 + lane], alpha * xl[(size_t)s_ * 64 + lane]);
}

// ---------------- bias + ELU (in place) -------------------------------------
__global__ void bias_elu_k(float* __restrict__ h, const float* __restrict__ b,
                           long total, int cmask) {
  long i = (long)blockIdx.x * blockDim.x + threadIdx.x;
  if (i >= total) return;
  float v = h[i] + b[(int)i & cmask];
  h[i] = v > 0.0f ? v : expf(v) - 1.0f;
}

// ---------------- mean pool over batch --------------------------------------
__global__ void pool_k(const float* __restrict__ h2, const int* __restrict__ batch,
                       float* __restrict__ pooled, float* __restrict__ cntg, int N) {
  long t = (long)blockIdx.x * blockDim.x + threadIdx.x;
  int n = (int)(t >> 6);
  int c = (int)(t & 63);
  if (n >= N) return;
  int g = batch[n];
  atomicAdd(&pooled[(size_t)g * 64 + c], h2[(size_t)n * 64 + c]);
  if (c == 0) atomicAdd(&cntg[g], 1.0f);
}

// ---------------- final MLP head --------------------------------------------
__global__ void final_mlp_k(const float* __restrict__ pooled, const float* __restrict__ cntg,
                            const float* __restrict__ u, const float* __restrict__ W1,
                            const float* __restrict__ b1, const float* __restrict__ Wh,
                            const float* __restrict__ bh, float* __restrict__ out) {
  __shared__ float feat[65];
  __shared__ float z[32];
  int g = blockIdx.x;
  int t = threadIdx.x;  // 64 threads
  float inv = 1.0f / fmaxf(cntg[g], 1.0f);
  feat[t] = pooled[(size_t)g * 64 + t] * inv;
  if (t == 0) feat[64] = u[g];
  __syncthreads();
  if (t < 32) {
    float a = b1[t];
    for (int k = 0; k < 65; ++k) a += feat[k] * W1[t * 65 + k];
    z[t] = fmaxf(a, 0.0f);
  }
  __syncthreads();
  if (t < 10) {
    float a = bh[t];
    for (int k = 0; k < 32; ++k) a += z[k] * Wh[t * 32 + k];
    out[g * 10 + t] = a;
  }
}

// ---------------------------------------------------------------------------
extern "C" void kernel_launch(void* const* d_in, const int* in_sizes, int n_in,
                              void* d_out, int out_size, void* d_ws, size_t ws_size,
                              hipStream_t stream) {
  const float* x      = (const float*)d_in[0];
  const int*   eidx   = (const int*)d_in[1];
  const float* eattr  = (const float*)d_in[2];
  const int*   batch  = (const int*)d_in[3];
  const float* u      = (const float*)d_in[4];
  const float* Wl1    = (const float*)d_in[5];
  const float* bl1    = (const float*)d_in[6];
  const float* Wr1    = (const float*)d_in[7];
  const float* br1    = (const float*)d_in[8];
  const float* We1    = (const float*)d_in[9];
  const float* att1   = (const float*)d_in[10];
  const float* b1     = (const float*)d_in[11];
  const float* Wl2    = (const float*)d_in[12];
  const float* bl2    = (const float*)d_in[13];
  const float* Wr2    = (const float*)d_in[14];
  const float* br2    = (const float*)d_in[15];
  const float* We2    = (const float*)d_in[16];
  const float* att2   = (const float*)d_in[17];
  const float* b2     = (const float*)d_in[18];
  const float* W_lin1 = (const float*)d_in[19];
  const float* b_lin1 = (const float*)d_in[20];
  const float* W_head = (const float*)d_in[21];
  const float* b_head = (const float*)d_in[22];

  const int N = in_sizes[0] / 128;
  const int E = in_sizes[1] / 2;
  const int G = in_sizes[4];
  const int Etot = E + N;
  const int* srcp = eidx;
  const int* dstp = eidx + E;

  float* ws  = (float*)d_ws;
  float* A   = ws;                       // N*128 : xl1, later xl2 (N*64)
  float* B   = A + (size_t)N * 128;      // N*128 : xr1, later xr2 (N*64)
  float* C   = B + (size_t)N * 128;      // N*128 : out1/h1, later out2/h2 (N*64)
  float* D   = C + (size_t)N * 128;      // Etot*4: exp(score) buffers
  float* Eb  = D + (size_t)Etot * 4;     // N*4   : softmax denominators
  float* Fls = Eb + (size_t)N * 4;       // N*3   : self-loop attr (sum->mean)
  float* Fcn = Fls + (size_t)N * 3;      // N     : in-degree count
  float* Pp  = Fcn + (size_t)N;          // G*64  : pooled sums
  float* Pc  = Pp + (size_t)G * 64;      // G     : per-graph node count

  // ---- zero accumulators (ws is re-poisoned to 0xAA before every call) ----
  hipMemsetAsync(Fls, 0, sizeof(float) * (size_t)N * 4, stream);   // loopsum+cnt
  hipMemsetAsync(Eb, 0, sizeof(float) * (size_t)N * 4, stream);    // denom1
  hipMemsetAsync(C, 0, sizeof(float) * (size_t)N * 128, stream);   // out1
  hipMemsetAsync(Pp, 0, sizeof(float) * ((size_t)G * 64 + G), stream);

  // ---- self-loop edge attrs (mean of incoming) ----
  loop_accum_k<<<(E + 255) / 256, 256, 0, stream>>>(dstp, eattr, Fls, Fcn, E);
  loop_norm_k<<<(N + 255) / 256, 256, 0, stream>>>(Fls, Fcn, N);

  // ---- layer 1 ----
  node_linear_k<128, 32><<<(N + 31) / 32, 256, 0, stream>>>(x, Wl1, bl1, A, N);
  node_linear_k<128, 32><<<(N + 31) / 32, 256, 0, stream>>>(x, Wr1, br1, B, N);
  score1_k<<<(Etot + 7) / 8, 256, 0, stream>>>(srcp, dstp, eattr, Fls, A, B, We1, att1, D, Eb, E, Etot);
  agg1_k<<<(Etot + 3) / 4, 256, 0, stream>>>(srcp, dstp, A, D, Eb, C, E, Etot);
  bias_elu_k<<<((long)N * 128 + 255) / 256, 256, 0, stream>>>(C, b1, (long)N * 128, 127);

  // ---- layer 2 ----
  node_linear_k<64, 64><<<(N + 63) / 64, 256, 0, stream>>>(C, Wl2, bl2, A, N);
  node_linear_k<64, 64><<<(N + 63) / 64, 256, 0, stream>>>(C, Wr2, br2, B, N);
  hipMemsetAsync(C, 0, sizeof(float) * (size_t)N * 64, stream);  // out2
  hipMemsetAsync(Eb, 0, sizeof(float) * (size_t)N, stream);      // denom2
  score2_k<<<(Etot + 3) / 4, 256, 0, stream>>>(srcp, dstp, eattr, Fls, A, B, We2, att2, D, Eb, E, Etot);
  agg2_k<<<(Etot + 3) / 4, 256, 0, stream>>>(srcp, dstp, A, D, Eb, C, E, Etot);
  bias_elu_k<<<((long)N * 64 + 255) / 256, 256, 0, stream>>>(C, b2, (long)N * 64, 63);

  // ---- pool + head ----
  pool_k<<<((long)N * 64 + 255) / 256, 256, 0, stream>>>(C, batch, Pp, Pc, N);
  final_mlp_k<<<G, 64, 0, stream>>>(Pp, Pc, u, W_lin1, b_lin1, W_head, b_head, (float*)d_out);
}

// Round 2
// 746.510 us; speedup vs baseline: 2.0195x; 2.0195x over previous
//
#include <hip/hip_runtime.h>
#include <math.h>

// ---------------------------------------------------------------------------
// TacticalGAT round 2: CSR-sorted (by dst) edge processing; fully fused
// per-node GATv2 layers (score + softmax + aggregate + bias + ELU in one
// kernel, zero float atomics).  Softmax without the max pass (scores O(1)).
// Self-loop attr (fill_value='mean') computed inline from the edge loop.
// ---------------------------------------------------------------------------

// ---------------- CSR build -------------------------------------------------
__global__ void hist_k(const int* __restrict__ dst, int* __restrict__ deg, int E) {
  int e = blockIdx.x * 256 + threadIdx.x;
  if (e < E) atomicAdd(&deg[dst[e]], 1);
}

__global__ void blocksum_k(const int* __restrict__ deg, int* __restrict__ bsum, int N) {
  __shared__ int s[256];
  int i = blockIdx.x * 256 + threadIdx.x;
  s[threadIdx.x] = (i < N) ? deg[i] : 0;
  __syncthreads();
  for (int off = 128; off; off >>= 1) {
    if (threadIdx.x < off) s[threadIdx.x] += s[threadIdx.x + off];
    __syncthreads();
  }
  if (threadIdx.x == 0) bsum[blockIdx.x] = s[0];
}

// exclusive scan of bsum[0..nb), nb <= 256, single block
__global__ void scan_bsum_k(int* __restrict__ bsum, int nb) {
  __shared__ int s[256];
  int t = threadIdx.x;
  s[t] = (t < nb) ? bsum[t] : 0;
  __syncthreads();
  for (int off = 1; off < 256; off <<= 1) {
    int v = (t >= off) ? s[t - off] : 0;
    __syncthreads();
    if (t >= off) s[t] += v;
    __syncthreads();
  }
  int excl = (t == 0) ? 0 : s[t - 1];
  if (t < nb) bsum[t] = excl;
}

__global__ void writeptr_k(const int* __restrict__ deg, const int* __restrict__ bsum,
                           int* __restrict__ rowptr, int* __restrict__ cursor, int N, int E) {
  __shared__ int s[256];
  int t = threadIdx.x;
  int i = blockIdx.x * 256 + t;
  s[t] = (i < N) ? deg[i] : 0;
  __syncthreads();
  for (int off = 1; off < 256; off <<= 1) {
    int v = (t >= off) ? s[t - off] : 0;
    __syncthreads();
    if (t >= off) s[t] += v;
    __syncthreads();
  }
  int excl = bsum[blockIdx.x] + ((t == 0) ? 0 : s[t - 1]);
  if (i < N) {
    rowptr[i] = excl;
    cursor[i] = excl;
  }
  if (i == N - 1) rowptr[N] = E;
}

__global__ void fill_k(const int* __restrict__ src, const int* __restrict__ dst,
                       const float* __restrict__ eattr, int* __restrict__ cursor,
                       int* __restrict__ srcs_s, float4* __restrict__ ea4, int E) {
  int e = blockIdx.x * 256 + threadIdx.x;
  if (e >= E) return;
  int d = dst[e];
  int pos = atomicAdd(&cursor[d], 1);
  srcs_s[pos] = src[e];
  ea4[pos] = make_float4(eattr[e * 3 + 0], eattr[e * 3 + 1], eattr[e * 3 + 2], 0.0f);
}

// ---------------- node linear: out[n,j] = sum_k X[n,k]*W[j,k] + b[j] --------
template <int J, int RB>
__global__ __launch_bounds__(256) void node_linear_k(
    const float* __restrict__ X, const float* __restrict__ W,
    const float* __restrict__ bias, float* __restrict__ out, int nrows) {
  constexpr int K = 128, KB = 64;
  constexpr int JG = J / 4;
  __shared__ __align__(16) float sW[KB][J];
  __shared__ float sX[RB][K + 1];

  int n0 = blockIdx.x * RB;
  for (int idx = threadIdx.x; idx < RB * K; idx += 256) {
    int r = idx >> 7, k = idx & 127;
    int n = n0 + r;
    sX[r][k] = (n < nrows) ? X[(size_t)n * K + k] : 0.0f;
  }
  int jg = threadIdx.x % JG;
  int rg = threadIdx.x / JG;

  float acc[4][4] = {};
  for (int kb = 0; kb < 2; ++kb) {
    __syncthreads();
    for (int idx = threadIdx.x; idx < KB * J; idx += 256) {
      int j = idx % J, k = idx / J;
      sW[k][j] = W[j * K + kb * KB + k];
    }
    __syncthreads();
#pragma unroll
    for (int k = 0; k < KB; ++k) {
      float4 w4 = *(const float4*)&sW[k][jg * 4];
#pragma unroll
      for (int i = 0; i < 4; ++i) {
        float xv = sX[rg * 4 + i][kb * KB + k];
        acc[i][0] += xv * w4.x;
        acc[i][1] += xv * w4.y;
        acc[i][2] += xv * w4.z;
        acc[i][3] += xv * w4.w;
      }
    }
  }
  float4 bv = *(const float4*)&bias[jg * 4];
#pragma unroll
  for (int i = 0; i < 4; ++i) {
    int n = n0 + rg * 4 + i;
    if (n < nrows) {
      float4 o;
      o.x = acc[i][0] + bv.x;
      o.y = acc[i][1] + bv.y;
      o.z = acc[i][2] + bv.z;
      o.w = acc[i][3] + bv.w;
      *(float4*)&out[(size_t)n * J + jg * 4] = o;
    }
  }
}

// ---------------- fused GATv2 layer 1 (H=4, C=32, concat) -------------------
// one wave per dst node; lane holds channels 2*lane, 2*lane+1 (same head).
__global__ __launch_bounds__(256) void gat1_fused_k(
    const int* __restrict__ rowptr, const int* __restrict__ srcs,
    const float4* __restrict__ ea4, const float* __restrict__ xl,
    const float* __restrict__ xr, const float* __restrict__ We,
    const float* __restrict__ att, const float* __restrict__ bias,
    float* __restrict__ out, int N) {
  int n = (blockIdx.x * 256 + threadIdx.x) >> 6;
  int lane = threadIdx.x & 63;
  if (n >= N) return;
  int c = lane * 2;
  float we00 = We[c * 3 + 0], we01 = We[c * 3 + 1], we02 = We[c * 3 + 2];
  float we10 = We[c * 3 + 3], we11 = We[c * 3 + 4], we12 = We[c * 3 + 5];
  float a0 = att[c], a1 = att[c + 1];
  float2 xrv = *(const float2*)&xr[(size_t)n * 128 + c];

  int beg = rowptr[n], end = rowptr[n + 1];
  float acc0 = 0.f, acc1 = 0.f, den = 0.f;
  float es0 = 0.f, es1 = 0.f, es2 = 0.f;

  for (int base = beg; base < end; base += 64) {
    int i = base + lane;
    int sp = 0;
    float4 eap = make_float4(0.f, 0.f, 0.f, 0.f);
    if (i < end) {
      sp = srcs[i];
      eap = ea4[i];
      es0 += eap.x; es1 += eap.y; es2 += eap.z;
    }
    int cnt = min(64, end - base);
    for (int j = 0; j < cnt; ++j) {
      int s = __shfl(sp, j);
      float e0 = __shfl(eap.x, j), e1 = __shfl(eap.y, j), e2 = __shfl(eap.z, j);
      float2 xlv = *(const float2*)&xl[(size_t)s * 128 + c];
      float m0 = xlv.x + xrv.x + e0 * we00 + e1 * we01 + e2 * we02;
      float m1 = xlv.y + xrv.y + e0 * we10 + e1 * we11 + e2 * we12;
      m0 = m0 > 0.f ? m0 : 0.2f * m0;
      m1 = m1 > 0.f ? m1 : 0.2f * m1;
      float v = m0 * a0 + m1 * a1;
      v += __shfl_xor(v, 1); v += __shfl_xor(v, 2);
      v += __shfl_xor(v, 4); v += __shfl_xor(v, 8);   // head = 16-lane group
      float ex = expf(v);
      den += ex;
      acc0 += ex * xlv.x;
      acc1 += ex * xlv.y;
    }
  }
  // loop attr = mean of incoming eattr
  for (int off = 32; off; off >>= 1) {
    es0 += __shfl_xor(es0, off); es1 += __shfl_xor(es1, off); es2 += __shfl_xor(es2, off);
  }
  float inv = 1.0f / fmaxf((float)(end - beg), 1.0f);
  es0 *= inv; es1 *= inv; es2 *= inv;
  // self loop
  float2 xls = *(const float2*)&xl[(size_t)n * 128 + c];
  float m0 = xls.x + xrv.x + es0 * we00 + es1 * we01 + es2 * we02;
  float m1 = xls.y + xrv.y + es0 * we10 + es1 * we11 + es2 * we12;
  m0 = m0 > 0.f ? m0 : 0.2f * m0;
  m1 = m1 > 0.f ? m1 : 0.2f * m1;
  float v = m0 * a0 + m1 * a1;
  v += __shfl_xor(v, 1); v += __shfl_xor(v, 2);
  v += __shfl_xor(v, 4); v += __shfl_xor(v, 8);
  float ex = expf(v);
  den += ex;
  acc0 += ex * xls.x;
  acc1 += ex * xls.y;

  float o0 = acc0 / den + bias[c];
  float o1 = acc1 / den + bias[c + 1];
  o0 = o0 > 0.f ? o0 : expf(o0) - 1.0f;   // ELU
  o1 = o1 > 0.f ? o1 : expf(o1) - 1.0f;
  *(float2*)&out[(size_t)n * 128 + c] = make_float2(o0, o1);
}

// ---------------- fused GATv2 layer 2 (H=1, C=64, mean) ---------------------
__global__ __launch_bounds__(256) void gat2_fused_k(
    const int* __restrict__ rowptr, const int* __restrict__ srcs,
    const float4* __restrict__ ea4, const float* __restrict__ xl,
    const float* __restrict__ xr, const float* __restrict__ We,
    const float* __restrict__ att, const float* __restrict__ bias,
    float* __restrict__ out, int N) {
  int n = (blockIdx.x * 256 + threadIdx.x) >> 6;
  int lane = threadIdx.x & 63;
  if (n >= N) return;
  float we0 = We[lane * 3 + 0], we1 = We[lane * 3 + 1], we2 = We[lane * 3 + 2];
  float a = att[lane];
  float xrv = xr[(size_t)n * 64 + lane];

  int beg = rowptr[n], end = rowptr[n + 1];
  float acc = 0.f, den = 0.f;
  float es0 = 0.f, es1 = 0.f, es2 = 0.f;

  for (int base = beg; base < end; base += 64) {
    int i = base + lane;
    int sp = 0;
    float4 eap = make_float4(0.f, 0.f, 0.f, 0.f);
    if (i < end) {
      sp = srcs[i];
      eap = ea4[i];
      es0 += eap.x; es1 += eap.y; es2 += eap.z;
    }
    int cnt = min(64, end - base);
    for (int j = 0; j < cnt; ++j) {
      int s = __shfl(sp, j);
      float e0 = __shfl(eap.x, j), e1 = __shfl(eap.y, j), e2 = __shfl(eap.z, j);
      float xlv = xl[(size_t)s * 64 + lane];
      float m = xlv + xrv + e0 * we0 + e1 * we1 + e2 * we2;
      m = m > 0.f ? m : 0.2f * m;
      float v = m * a;
      v += __shfl_xor(v, 1); v += __shfl_xor(v, 2); v += __shfl_xor(v, 4);
      v += __shfl_xor(v, 8); v += __shfl_xor(v, 16); v += __shfl_xor(v, 32);
      float ex = expf(v);
      den += ex;
      acc += ex * xlv;
    }
  }
  for (int off = 32; off; off >>= 1) {
    es0 += __shfl_xor(es0, off); es1 += __shfl_xor(es1, off); es2 += __shfl_xor(es2, off);
  }
  float inv = 1.0f / fmaxf((float)(end - beg), 1.0f);
  es0 *= inv; es1 *= inv; es2 *= inv;
  float xls = xl[(size_t)n * 64 + lane];
  float m = xls + xrv + es0 * we0 + es1 * we1 + es2 * we2;
  m = m > 0.f ? m : 0.2f * m;
  float v = m * a;
  v += __shfl_xor(v, 1); v += __shfl_xor(v, 2); v += __shfl_xor(v, 4);
  v += __shfl_xor(v, 8); v += __shfl_xor(v, 16); v += __shfl_xor(v, 32);
  float ex = expf(v);
  den += ex;
  acc += ex * xls;

  float o = acc / den + bias[lane];
  o = o > 0.f ? o : expf(o) - 1.0f;   // ELU
  out[(size_t)n * 64 + lane] = o;
}

// ---------------- mean pool over batch --------------------------------------
__global__ void pool_k(const float* __restrict__ h2, const int* __restrict__ batch,
                       float* __restrict__ pooled, float* __restrict__ cntg, int N) {
  long t = (long)blockIdx.x * blockDim.x + threadIdx.x;
  int n = (int)(t >> 6);
  int c = (int)(t & 63);
  if (n >= N) return;
  int g = batch[n];
  atomicAdd(&pooled[(size_t)g * 64 + c], h2[(size_t)n * 64 + c]);
  if (c == 0) atomicAdd(&cntg[g], 1.0f);
}

// ---------------- final MLP head --------------------------------------------
__global__ void final_mlp_k(const float* __restrict__ pooled, const float* __restrict__ cntg,
                            const float* __restrict__ u, const float* __restrict__ W1,
                            const float* __restrict__ b1, const float* __restrict__ Wh,
                            const float* __restrict__ bh, float* __restrict__ out) {
  __shared__ float feat[65];
  __shared__ float z[32];
  int g = blockIdx.x;
  int t = threadIdx.x;  // 64 threads
  float inv = 1.0f / fmaxf(cntg[g], 1.0f);
  feat[t] = pooled[(size_t)g * 64 + t] * inv;
  if (t == 0) feat[64] = u[g];
  __syncthreads();
  if (t < 32) {
    float a = b1[t];
    for (int k = 0; k < 65; ++k) a += feat[k] * W1[t * 65 + k];
    z[t] = fmaxf(a, 0.0f);
  }
  __syncthreads();
  if (t < 10) {
    float a = bh[t];
    for (int k = 0; k < 32; ++k) a += z[k] * Wh[t * 32 + k];
    out[g * 10 + t] = a;
  }
}

// ---------------------------------------------------------------------------
extern "C" void kernel_launch(void* const* d_in, const int* in_sizes, int n_in,
                              void* d_out, int out_size, void* d_ws, size_t ws_size,
                              hipStream_t stream) {
  const float* x      = (const float*)d_in[0];
  const int*   eidx   = (const int*)d_in[1];
  const float* eattr  = (const float*)d_in[2];
  const int*   batch  = (const int*)d_in[3];
  const float* u      = (const float*)d_in[4];
  const float* Wl1    = (const float*)d_in[5];
  const float* bl1    = (const float*)d_in[6];
  const float* Wr1    = (const float*)d_in[7];
  const float* br1    = (const float*)d_in[8];
  const float* We1    = (const float*)d_in[9];
  const float* att1   = (const float*)d_in[10];
  const float* b1     = (const float*)d_in[11];
  const float* Wl2    = (const float*)d_in[12];
  const float* bl2    = (const float*)d_in[13];
  const float* Wr2    = (const float*)d_in[14];
  const float* br2    = (const float*)d_in[15];
  const float* We2    = (const float*)d_in[16];
  const float* att2   = (const float*)d_in[17];
  const float* b2     = (const float*)d_in[18];
  const float* W_lin1 = (const float*)d_in[19];
  const float* b_lin1 = (const float*)d_in[20];
  const float* W_head = (const float*)d_in[21];
  const float* b_head = (const float*)d_in[22];

  const int N = in_sizes[0] / 128;
  const int E = in_sizes[1] / 2;
  const int G = in_sizes[4];
  const int* srcp = eidx;
  const int* dstp = eidx + E;

  // ---- workspace layout (buf1/2/3 reused across layers) ----
  float* buf1 = (float*)d_ws;                       // xl1 (N*128) -> xl2 (N*64)
  float* buf2 = buf1 + (size_t)N * 128;             // xr1 (N*128) -> xr2 (N*64)
  float* buf3 = buf2 + (size_t)N * 128;             // h1  (N*128) -> h2  (N*64)
  float4* ea4 = (float4*)(buf3 + (size_t)N * 128);  // E sorted edge attrs
  int* srcs_s = (int*)(ea4 + E);                    // E sorted src ids
  int* deg    = srcs_s + E;                         // N
  int* rowptr = deg + N;                            // N+1
  int* cursor = rowptr + N + 1;                     // N
  int* bsum   = cursor + N;                         // 256
  float* pooled = (float*)(bsum + 256);             // G*64
  float* pcnt   = pooled + (size_t)G * 64;          // G

  const int nb = (N + 255) / 256;

  // ---- CSR build (sort edges by dst) ----
  hipMemsetAsync(deg, 0, sizeof(int) * (size_t)N, stream);
  hist_k<<<(E + 255) / 256, 256, 0, stream>>>(dstp, deg, E);
  blocksum_k<<<nb, 256, 0, stream>>>(deg, bsum, N);
  scan_bsum_k<<<1, 256, 0, stream>>>(bsum, nb);
  writeptr_k<<<nb, 256, 0, stream>>>(deg, bsum, rowptr, cursor, N, E);
  fill_k<<<(E + 255) / 256, 256, 0, stream>>>(srcp, dstp, eattr, cursor, srcs_s, ea4, E);

  // ---- layer 1 ----
  node_linear_k<128, 32><<<(N + 31) / 32, 256, 0, stream>>>(x, Wl1, bl1, buf1, N);
  node_linear_k<128, 32><<<(N + 31) / 32, 256, 0, stream>>>(x, Wr1, br1, buf2, N);
  gat1_fused_k<<<(N + 3) / 4, 256, 0, stream>>>(rowptr, srcs_s, ea4, buf1, buf2,
                                                We1, att1, b1, buf3, N);

  // ---- layer 2 ----
  node_linear_k<64, 64><<<(N + 63) / 64, 256, 0, stream>>>(buf3, Wl2, bl2, buf1, N);
  node_linear_k<64, 64><<<(N + 63) / 64, 256, 0, stream>>>(buf3, Wr2, br2, buf2, N);
  gat2_fused_k<<<(N + 3) / 4, 256, 0, stream>>>(rowptr, srcs_s, ea4, buf1, buf2,
                                                We2, att2, b2, buf3, N);

  // ---- pool + head ----
  hipMemsetAsync(pooled, 0, sizeof(float) * ((size_t)G * 64 + G), stream);
  pool_k<<<((long)N * 64 + 255) / 256, 256, 0, stream>>>(buf3, batch, pooled, pcnt, N);
  final_mlp_k<<<G, 64, 0, stream>>>(pooled, pcnt, u, W_lin1, b_lin1, W_head, b_head,
                                    (float*)d_out);
}

// Round 3
// 710.596 us; speedup vs baseline: 2.1215x; 1.0505x over previous
//
#include <hip/hip_runtime.h>
#include <math.h>

// ---------------------------------------------------------------------------
// TacticalGAT round 3: fused GATv2 layers restructured into batched two-phase
// (edge-parallel score w/ per-lane reduction, then channel-parallel aggregate
// from LDS-staged rows).  No per-edge shuffle chains, exp 8-wide, rows read
// from global once per batch (coalesced) and reused for score + aggregate.
// ---------------------------------------------------------------------------

__device__ __forceinline__ void wbar() { __builtin_amdgcn_wave_barrier(); }

// ---------------- CSR build -------------------------------------------------
__global__ void hist_k(const int* __restrict__ dst, int* __restrict__ deg, int E) {
  int e = blockIdx.x * 256 + threadIdx.x;
  if (e < E) atomicAdd(&deg[dst[e]], 1);
}

__global__ void blocksum_k(const int* __restrict__ deg, int* __restrict__ bsum, int N) {
  __shared__ int s[256];
  int i = blockIdx.x * 256 + threadIdx.x;
  s[threadIdx.x] = (i < N) ? deg[i] : 0;
  __syncthreads();
  for (int off = 128; off; off >>= 1) {
    if (threadIdx.x < off) s[threadIdx.x] += s[threadIdx.x + off];
    __syncthreads();
  }
  if (threadIdx.x == 0) bsum[blockIdx.x] = s[0];
}

__global__ void scan_bsum_k(int* __restrict__ bsum, int nb) {
  __shared__ int s[256];
  int t = threadIdx.x;
  s[t] = (t < nb) ? bsum[t] : 0;
  __syncthreads();
  for (int off = 1; off < 256; off <<= 1) {
    int v = (t >= off) ? s[t - off] : 0;
    __syncthreads();
    if (t >= off) s[t] += v;
    __syncthreads();
  }
  int excl = (t == 0) ? 0 : s[t - 1];
  if (t < nb) bsum[t] = excl;
}

__global__ void writeptr_k(const int* __restrict__ deg, const int* __restrict__ bsum,
                           int* __restrict__ rowptr, int* __restrict__ cursor, int N, int E) {
  __shared__ int s[256];
  int t = threadIdx.x;
  int i = blockIdx.x * 256 + t;
  s[t] = (i < N) ? deg[i] : 0;
  __syncthreads();
  for (int off = 1; off < 256; off <<= 1) {
    int v = (t >= off) ? s[t - off] : 0;
    __syncthreads();
    if (t >= off) s[t] += v;
    __syncthreads();
  }
  int excl = bsum[blockIdx.x] + ((t == 0) ? 0 : s[t - 1]);
  if (i < N) {
    rowptr[i] = excl;
    cursor[i] = excl;
  }
  if (i == N - 1) rowptr[N] = E;
}

__global__ void fill_k(const int* __restrict__ src, const int* __restrict__ dst,
                       const float* __restrict__ eattr, int* __restrict__ cursor,
                       int* __restrict__ srcs_s, float4* __restrict__ ea4, int E) {
  int e = blockIdx.x * 256 + threadIdx.x;
  if (e >= E) return;
  int d = dst[e];
  int pos = atomicAdd(&cursor[d], 1);
  srcs_s[pos] = src[e];
  ea4[pos] = make_float4(eattr[e * 3 + 0], eattr[e * 3 + 1], eattr[e * 3 + 2], 0.0f);
}

// ---------------- node linear: out[n,j] = sum_k X[n,k]*W[j,k] + b[j] --------
template <int J, int RB>
__global__ __launch_bounds__(256) void node_linear_k(
    const float* __restrict__ X, const float* __restrict__ W,
    const float* __restrict__ bias, float* __restrict__ out, int nrows) {
  constexpr int K = 128, KB = 64;
  constexpr int JG = J / 4;
  __shared__ __align__(16) float sW[KB][J];
  __shared__ float sX[RB][K + 1];

  int n0 = blockIdx.x * RB;
  for (int idx = threadIdx.x; idx < RB * K; idx += 256) {
    int r = idx >> 7, k = idx & 127;
    int n = n0 + r;
    sX[r][k] = (n < nrows) ? X[(size_t)n * K + k] : 0.0f;
  }
  int jg = threadIdx.x % JG;
  int rg = threadIdx.x / JG;

  float acc[4][4] = {};
  for (int kb = 0; kb < 2; ++kb) {
    __syncthreads();
    for (int idx = threadIdx.x; idx < KB * J; idx += 256) {
      int j = idx % J, k = idx / J;
      sW[k][j] = W[j * K + kb * KB + k];
    }
    __syncthreads();
#pragma unroll
    for (int k = 0; k < KB; ++k) {
      float4 w4 = *(const float4*)&sW[k][jg * 4];
#pragma unroll
      for (int i = 0; i < 4; ++i) {
        float xv = sX[rg * 4 + i][kb * KB + k];
        acc[i][0] += xv * w4.x;
        acc[i][1] += xv * w4.y;
        acc[i][2] += xv * w4.z;
        acc[i][3] += xv * w4.w;
      }
    }
  }
  float4 bv = *(const float4*)&bias[jg * 4];
#pragma unroll
  for (int i = 0; i < 4; ++i) {
    int n = n0 + rg * 4 + i;
    if (n < nrows) {
      float4 o;
      o.x = acc[i][0] + bv.x;
      o.y = acc[i][1] + bv.y;
      o.z = acc[i][2] + bv.z;
      o.w = acc[i][3] + bv.w;
      *(float4*)&out[(size_t)n * J + jg * 4] = o;
    }
  }
}

// ---------------- fused GATv2 layer 1 (H=4, C=32, concat, 128 out) ----------
// one wave per node; 8-edge batches; rows staged in LDS (pad 132).
__global__ __launch_bounds__(256) void gat1_fused_k(
    const int* __restrict__ rowptr, const int* __restrict__ srcs,
    const float4* __restrict__ ea4, const float* __restrict__ xl,
    const float* __restrict__ xr, const float* __restrict__ We,
    const float* __restrict__ att, const float* __restrict__ bias,
    float* __restrict__ out, int N) {
  __shared__ __align__(16) float4 w4s[136];          // idx = c + (c>>4)
  __shared__ __align__(16) float lds[4 * 1096];      // per wave: rows 8*132, sex 40
  int tid = threadIdx.x;
  if (tid < 128) {
    int c = tid;
    w4s[c + (c >> 4)] = make_float4(We[c * 3], We[c * 3 + 1], We[c * 3 + 2], att[c]);
  }
  __syncthreads();

  int wv = tid >> 6, lane = tid & 63;
  float* wbase = &lds[wv * 1096];
  float* rows = wbase;            // 8 rows * 132
  float* sex  = wbase + 1056;     // 8 edges * 4 heads, stride 5

  int n = blockIdx.x * 4 + wv;
  if (n >= N) return;

  // phase-A lane mapping: e8 = edge-in-batch, (h,chalf) = channel chunk
  int e8 = lane >> 3;
  int r = lane & 7;
  int h = r >> 1, chalf = r & 1;
  int cbaseA = h * 32 + chalf * 16;
  // phase-B channel mapping
  int hL = lane >> 5;
  int hH = 2 + hL;

  // preload xr chunk for phase A (registers)
  float xrA[16];
#pragma unroll
  for (int i = 0; i < 16; ++i) xrA[i] = xr[(size_t)n * 128 + cbaseA + i];

  int beg = rowptr[n], end = rowptr[n + 1];
  int elem4 = lane & 31, jhalf = lane >> 5;

  float es0 = 0.f, es1 = 0.f, es2 = 0.f;
  float accL = 0.f, accH = 0.f, denL = 0.f, denH = 0.f;

  for (int base = beg; base < end; base += 8) {
    // ---- stage 8 src rows into LDS (coalesced float4) ----
    wbar();
#pragma unroll
    for (int rr = 0; rr < 4; ++rr) {
      int j = rr * 2 + jhalf;
      int gi = base + j;
      int s = (gi < end) ? srcs[gi] : n;
      float4 v4 = ((const float4*)xl)[(size_t)s * 32 + elem4];
      *(float4*)&rows[j * 132 + elem4 * 4] = v4;
    }
    wbar();
    // ---- phase A: score per (edge, head) ----
    bool valid = (base + e8) < end;
    float4 ea_e = valid ? ea4[base + e8] : make_float4(0.f, 0.f, 0.f, 0.f);
    if (r == 0) { es0 += ea_e.x; es1 += ea_e.y; es2 += ea_e.z; }
    float v = 0.f;
    const float4* rv4 = (const float4*)&rows[e8 * 132 + cbaseA];
#pragma unroll
    for (int i4 = 0; i4 < 4; ++i4) {
      float4 rv = rv4[i4];
#pragma unroll
      for (int q = 0; q < 4; ++q) {
        int i = i4 * 4 + q;
        int c = cbaseA + i;
        float4 w = w4s[c + (c >> 4)];
        float rvq = (q == 0) ? rv.x : (q == 1) ? rv.y : (q == 2) ? rv.z : rv.w;
        float m = rvq + xrA[i] + ea_e.x * w.x + ea_e.y * w.y + ea_e.z * w.z;
        m = fmaxf(m, 0.2f * m);
        v = fmaf(m, w.w, v);
      }
    }
    v += __shfl_xor(v, 1);
    float ex = valid ? __expf(v) : 0.f;
    if (chalf == 0) sex[e8 * 5 + h] = ex;
    wbar();
    // ---- phase B: aggregate (channel per lane) ----
#pragma unroll
    for (int j = 0; j < 8; ++j) {
      float exl = sex[j * 5 + hL];
      float exh = sex[j * 5 + hH];
      accL = fmaf(exl, rows[j * 132 + lane], accL);
      accH = fmaf(exh, rows[j * 132 + 64 + lane], accH);
      denL += exl;
      denH += exh;
    }
  }

  // ---- self loop (attr = mean of incoming) ----
#pragma unroll
  for (int off = 1; off < 64; off <<= 1) {
    es0 += __shfl_xor(es0, off);
    es1 += __shfl_xor(es1, off);
    es2 += __shfl_xor(es2, off);
  }
  float inv = 1.0f / fmaxf((float)(end - beg), 1.0f);
  es0 *= inv; es1 *= inv; es2 *= inv;

  float xlsL = xl[(size_t)n * 128 + lane];
  float xlsH = xl[(size_t)n * 128 + 64 + lane];
  float xrL = xr[(size_t)n * 128 + lane];
  float xrH = xr[(size_t)n * 128 + 64 + lane];
  float4 wL = w4s[lane + (lane >> 4)];
  int cH = lane + 64;
  float4 wH = w4s[cH + (cH >> 4)];
  float mL = xlsL + xrL + es0 * wL.x + es1 * wL.y + es2 * wL.z;
  mL = fmaxf(mL, 0.2f * mL);
  float tL = mL * wL.w;
  float mH = xlsH + xrH + es0 * wH.x + es1 * wH.y + es2 * wH.z;
  mH = fmaxf(mH, 0.2f * mH);
  float tH = mH * wH.w;
#pragma unroll
  for (int off = 1; off < 32; off <<= 1) {
    tL += __shfl_xor(tL, off);
    tH += __shfl_xor(tH, off);
  }
  float exL = __expf(tL), exH = __expf(tH);
  denL += exL; accL = fmaf(exL, xlsL, accL);
  denH += exH; accH = fmaf(exH, xlsH, accH);

  float oL = accL / denL + bias[lane];
  float oH = accH / denH + bias[64 + lane];
  oL = oL > 0.f ? oL : __expf(oL) - 1.0f;  // ELU
  oH = oH > 0.f ? oH : __expf(oH) - 1.0f;
  out[(size_t)n * 128 + lane] = oL;
  out[(size_t)n * 128 + 64 + lane] = oH;
}

// ---------------- fused GATv2 layer 2 (H=1, C=64, mean) ---------------------
__global__ __launch_bounds__(256) void gat2_fused_k(
    const int* __restrict__ rowptr, const int* __restrict__ srcs,
    const float4* __restrict__ ea4, const float* __restrict__ xl,
    const float* __restrict__ xr, const float* __restrict__ We,
    const float* __restrict__ att, const float* __restrict__ bias,
    float* __restrict__ out, int N) {
  __shared__ __align__(16) float4 w4s[72];          // idx = c + (c>>3)
  __shared__ __align__(16) float lds[4 * 552];      // per wave: rows 8*68, sex 8
  int tid = threadIdx.x;
  if (tid < 64) {
    int c = tid;
    w4s[c + (c >> 3)] = make_float4(We[c * 3], We[c * 3 + 1], We[c * 3 + 2], att[c]);
  }
  __syncthreads();

  int wv = tid >> 6, lane = tid & 63;
  float* wbase = &lds[wv * 552];
  float* rows = wbase;          // 8 rows * 68
  float* sex  = wbase + 544;    // 8

  int n = blockIdx.x * 4 + wv;
  if (n >= N) return;

  int e8 = lane >> 3;
  int oct = lane & 7;
  int cbase = oct * 8;

  float xrA[8];
#pragma unroll
  for (int i = 0; i < 8; ++i) xrA[i] = xr[(size_t)n * 64 + cbase + i];

  int beg = rowptr[n], end = rowptr[n + 1];
  int elem4 = lane & 15, jq = lane >> 4;

  float es0 = 0.f, es1 = 0.f, es2 = 0.f;
  float acc = 0.f, den = 0.f;

  for (int base = beg; base < end; base += 8) {
    wbar();
#pragma unroll
    for (int rr = 0; rr < 2; ++rr) {
      int j = rr * 4 + jq;
      int gi = base + j;
      int s = (gi < end) ? srcs[gi] : n;
      float4 v4 = ((const float4*)xl)[(size_t)s * 16 + elem4];
      *(float4*)&rows[j * 68 + elem4 * 4] = v4;
    }
    wbar();
    bool valid = (base + e8) < end;
    float4 ea_e = valid ? ea4[base + e8] : make_float4(0.f, 0.f, 0.f, 0.f);
    if (oct == 0) { es0 += ea_e.x; es1 += ea_e.y; es2 += ea_e.z; }
    float v = 0.f;
    const float4* rv4 = (const float4*)&rows[e8 * 68 + cbase];
#pragma unroll
    for (int i4 = 0; i4 < 2; ++i4) {
      float4 rv = rv4[i4];
#pragma unroll
      for (int q = 0; q < 4; ++q) {
        int i = i4 * 4 + q;
        int c = cbase + i;
        float4 w = w4s[c + (c >> 3)];
        float rvq = (q == 0) ? rv.x : (q == 1) ? rv.y : (q == 2) ? rv.z : rv.w;
        float m = rvq + xrA[i] + ea_e.x * w.x + ea_e.y * w.y + ea_e.z * w.z;
        m = fmaxf(m, 0.2f * m);
        v = fmaf(m, w.w, v);
      }
    }
    v += __shfl_xor(v, 1);
    v += __shfl_xor(v, 2);
    v += __shfl_xor(v, 4);
    float ex = valid ? __expf(v) : 0.f;
    if (oct == 0) sex[e8] = ex;
    wbar();
#pragma unroll
    for (int j = 0; j < 8; ++j) {
      float exj = sex[j];
      acc = fmaf(exj, rows[j * 68 + lane], acc);
      den += exj;
    }
  }

#pragma unroll
  for (int off = 1; off < 64; off <<= 1) {
    es0 += __shfl_xor(es0, off);
    es1 += __shfl_xor(es1, off);
    es2 += __shfl_xor(es2, off);
  }
  float inv = 1.0f / fmaxf((float)(end - beg), 1.0f);
  es0 *= inv; es1 *= inv; es2 *= inv;

  float xls = xl[(size_t)n * 64 + lane];
  float xrv = xr[(size_t)n * 64 + lane];
  float4 w = w4s[lane + (lane >> 3)];
  float m = xls + xrv + es0 * w.x + es1 * w.y + es2 * w.z;
  m = fmaxf(m, 0.2f * m);
  float t = m * w.w;
#pragma unroll
  for (int off = 1; off < 64; off <<= 1) t += __shfl_xor(t, off);
  float ex = __expf(t);
  den += ex;
  acc = fmaf(ex, xls, acc);

  float o = acc / den + bias[lane];
  o = o > 0.f ? o : __expf(o) - 1.0f;  // ELU
  out[(size_t)n * 64 + lane] = o;
}

// ---------------- mean pool over batch --------------------------------------
__global__ void pool_k(const float* __restrict__ h2, const int* __restrict__ batch,
                       float* __restrict__ pooled, float* __restrict__ cntg, int N) {
  long t = (long)blockIdx.x * blockDim.x + threadIdx.x;
  int n = (int)(t >> 6);
  int c = (int)(t & 63);
  if (n >= N) return;
  int g = batch[n];
  atomicAdd(&pooled[(size_t)g * 64 + c], h2[(size_t)n * 64 + c]);
  if (c == 0) atomicAdd(&cntg[g], 1.0f);
}

// ---------------- final MLP head --------------------------------------------
__global__ void final_mlp_k(const float* __restrict__ pooled, const float* __restrict__ cntg,
                            const float* __restrict__ u, const float* __restrict__ W1,
                            const float* __restrict__ b1, const float* __restrict__ Wh,
                            const float* __restrict__ bh, float* __restrict__ out) {
  __shared__ float feat[65];
  __shared__ float z[32];
  int g = blockIdx.x;
  int t = threadIdx.x;  // 64 threads
  float inv = 1.0f / fmaxf(cntg[g], 1.0f);
  feat[t] = pooled[(size_t)g * 64 + t] * inv;
  if (t == 0) feat[64] = u[g];
  __syncthreads();
  if (t < 32) {
    float a = b1[t];
    for (int k = 0; k < 65; ++k) a += feat[k] * W1[t * 65 + k];
    z[t] = fmaxf(a, 0.0f);
  }
  __syncthreads();
  if (t < 10) {
    float a = bh[t];
    for (int k = 0; k < 32; ++k) a += z[k] * Wh[t * 32 + k];
    out[g * 10 + t] = a;
  }
}

// ---------------------------------------------------------------------------
extern "C" void kernel_launch(void* const* d_in, const int* in_sizes, int n_in,
                              void* d_out, int out_size, void* d_ws, size_t ws_size,
                              hipStream_t stream) {
  const float* x      = (const float*)d_in[0];
  const int*   eidx   = (const int*)d_in[1];
  const float* eattr  = (const float*)d_in[2];
  const int*   batch  = (const int*)d_in[3];
  const float* u      = (const float*)d_in[4];
  const float* Wl1    = (const float*)d_in[5];
  const float* bl1    = (const float*)d_in[6];
  const float* Wr1    = (const float*)d_in[7];
  const float* br1    = (const float*)d_in[8];
  const float* We1    = (const float*)d_in[9];
  const float* att1   = (const float*)d_in[10];
  const float* b1     = (const float*)d_in[11];
  const float* Wl2    = (const float*)d_in[12];
  const float* bl2    = (const float*)d_in[13];
  const float* Wr2    = (const float*)d_in[14];
  const float* br2    = (const float*)d_in[15];
  const float* We2    = (const float*)d_in[16];
  const float* att2   = (const float*)d_in[17];
  const float* b2     = (const float*)d_in[18];
  const float* W_lin1 = (const float*)d_in[19];
  const float* b_lin1 = (const float*)d_in[20];
  const float* W_head = (const float*)d_in[21];
  const float* b_head = (const float*)d_in[22];

  const int N = in_sizes[0] / 128;
  const int E = in_sizes[1] / 2;
  const int G = in_sizes[4];
  const int* srcp = eidx;
  const int* dstp = eidx + E;

  // ---- workspace layout ----
  float* buf1 = (float*)d_ws;                       // xl1 (N*128) -> xl2 (N*64)
  float* buf2 = buf1 + (size_t)N * 128;             // xr1 (N*128) -> xr2 (N*64)
  float* buf3 = buf2 + (size_t)N * 128;             // h1  (N*128) -> h2  (N*64)
  float4* ea4 = (float4*)(buf3 + (size_t)N * 128);  // E sorted edge attrs
  int* srcs_s = (int*)(ea4 + E);                    // E sorted src ids
  int* deg    = srcs_s + E;                         // N
  int* rowptr = deg + N;                            // N+1
  int* cursor = rowptr + N + 1;                     // N
  int* bsum   = cursor + N;                         // 256
  float* pooled = (float*)(bsum + 256);             // G*64
  float* pcnt   = pooled + (size_t)G * 64;          // G

  const int nb = (N + 255) / 256;

  // ---- CSR build (sort edges by dst) ----
  hipMemsetAsync(deg, 0, sizeof(int) * (size_t)N, stream);
  hist_k<<<(E + 255) / 256, 256, 0, stream>>>(dstp, deg, E);
  blocksum_k<<<nb, 256, 0, stream>>>(deg, bsum, N);
  scan_bsum_k<<<1, 256, 0, stream>>>(bsum, nb);
  writeptr_k<<<nb, 256, 0, stream>>>(deg, bsum, rowptr, cursor, N, E);
  fill_k<<<(E + 255) / 256, 256, 0, stream>>>(srcp, dstp, eattr, cursor, srcs_s, ea4, E);

  // ---- layer 1 ----
  node_linear_k<128, 32><<<(N + 31) / 32, 256, 0, stream>>>(x, Wl1, bl1, buf1, N);
  node_linear_k<128, 32><<<(N + 31) / 32, 256, 0, stream>>>(x, Wr1, br1, buf2, N);
  gat1_fused_k<<<(N + 3) / 4, 256, 0, stream>>>(rowptr, srcs_s, ea4, buf1, buf2,
                                                We1, att1, b1, buf3, N);

  // ---- layer 2 ----
  node_linear_k<64, 64><<<(N + 63) / 64, 256, 0, stream>>>(buf3, Wl2, bl2, buf1, N);
  node_linear_k<64, 64><<<(N + 63) / 64, 256, 0, stream>>>(buf3, Wr2, br2, buf2, N);
  gat2_fused_k<<<(N + 3) / 4, 256, 0, stream>>>(rowptr, srcs_s, ea4, buf1, buf2,
                                                We2, att2, b2, buf3, N);

  // ---- pool + head ----
  hipMemsetAsync(pooled, 0, sizeof(float) * ((size_t)G * 64 + G), stream);
  pool_k<<<((long)N * 64 + 255) / 256, 256, 0, stream>>>(buf3, batch, pooled, pcnt, N);
  final_mlp_k<<<G, 64, 0, stream>>>(pooled, pcnt, u, W_lin1, b_lin1, W_head, b_head,
                                    (float*)d_out);
}